// Round 6
// baseline (304.643 us; speedup 1.0000x reference)
//
#include <hip/hip_runtime.h>
#include <math.h>

#define NB 4096
#define ND 1024
#define SCALEF 20.0f
#define TILES 32   // 4096 / 128 tiles per dimension
#define GRID (TILES * TILES)
// epilogue compensation: elements scaled by 256 at convert -> dot x 65536
#define EPI_SCALE (SCALEF / 65536.0f)

typedef float floatx4 __attribute__((ext_vector_type(4)));
typedef long longx2 __attribute__((ext_vector_type(2)));

// ---------------------------------------------------------------------------
// Kernel 1: fused L2-normalize + scale-by-256 + fp32->fp8(e4m3 OCP) convert.
// Permuted row layout, ITERATION-CONTIGUOUS: element k = s*32 + q*8 + j
// (s = K32 step, q = quad, j = 0..7) lives at byte
//   pos(k) = (s>>1)*64 + q*16 + (s&1)*8 + j
// One wave per row; lane l handles 16-B cell l (sp=l>>2, q=l&3).
// Also zeroes rowsum[] and the finalize counter.
// ---------------------------------------------------------------------------
__global__ __launch_bounds__(256) void mnrl_norm_cvt(
    const float* __restrict__ A, const float* __restrict__ P,
    unsigned char* __restrict__ A8, unsigned char* __restrict__ P8,
    float* __restrict__ rowsum, int* __restrict__ counter) {
    int row = blockIdx.x * 4 + (threadIdx.x >> 6);  // 0..8191
    int lane = threadIdx.x & 63;
    bool is_a = row < NB;
    const float* src = is_a ? (A + (size_t)row * ND)
                            : (P + (size_t)(row - NB) * ND);
    unsigned char* dst = is_a ? (A8 + (size_t)row * ND)
                              : (P8 + (size_t)(row - NB) * ND);

    int g0 = (lane >> 2) * 64 + (lane & 3) * 8;  // k of step 2sp, quad q
    float4 va = *(const float4*)(src + g0);
    float4 vb = *(const float4*)(src + g0 + 4);
    float4 vc = *(const float4*)(src + g0 + 32);  // step 2sp+1
    float4 vd = *(const float4*)(src + g0 + 36);

    float ss = va.x * va.x + va.y * va.y + va.z * va.z + va.w * va.w +
               vb.x * vb.x + vb.y * vb.y + vb.z * vb.z + vb.w * vb.w +
               vc.x * vc.x + vc.y * vc.y + vc.z * vc.z + vc.w * vc.w +
               vd.x * vd.x + vd.y * vd.y + vd.z * vd.z + vd.w * vd.w;
#pragma unroll
    for (int off = 32; off > 0; off >>= 1) ss += __shfl_xor(ss, off, 64);
    float inv = 256.0f / fmaxf(sqrtf(ss), 1e-8f);  // 256x folded in here

    int w0 = __builtin_amdgcn_cvt_pk_fp8_f32(va.x * inv, va.y * inv, 0, false);
    w0 = __builtin_amdgcn_cvt_pk_fp8_f32(va.z * inv, va.w * inv, w0, true);
    int w1 = __builtin_amdgcn_cvt_pk_fp8_f32(vb.x * inv, vb.y * inv, 0, false);
    w1 = __builtin_amdgcn_cvt_pk_fp8_f32(vb.z * inv, vb.w * inv, w1, true);
    int w2 = __builtin_amdgcn_cvt_pk_fp8_f32(vc.x * inv, vc.y * inv, 0, false);
    w2 = __builtin_amdgcn_cvt_pk_fp8_f32(vc.z * inv, vc.w * inv, w2, true);
    int w3 = __builtin_amdgcn_cvt_pk_fp8_f32(vd.x * inv, vd.y * inv, 0, false);
    w3 = __builtin_amdgcn_cvt_pk_fp8_f32(vd.z * inv, vd.w * inv, w3, true);
    int4 w; w.x = w0; w.y = w1; w.z = w2; w.w = w3;
    *(int4*)(dst + lane * 16) = w;

    if (is_a && lane == 0) rowsum[row] = 0.0f;
    if (blockIdx.x == 0 && threadIdx.x == 0) *counter = 0;
}

// ---------------------------------------------------------------------------
// Kernel 2: 128x128-tile fp8 MFMA GEMM + fused exp-sum + diag + last-block
// finalize. BK=128, 8 iters. REGISTER-PREFETCH PIPELINE:
//   top barrier -> ds_write prefetched regs (the only vmcnt wait, with a
//   full compute phase of slack) -> barrier -> issue next iter's
//   global_load_dwordx4 -> ds_read+MFMA.
// Thread t stages 4 16-B chunks per matrix: chunk c = t + 256*i, row = c>>3,
// ch = c&7; global addr row*ND + it*128 + ch*16 (8 consecutive threads = one
// full 128-B line); LDS byte = row*128 + (ch^(row&7))*16 (consecutive 8
// lanes write 8 distinct bank groups -> conflict-free). Frag read slot =
// (spl*4+quad)^(l16&7)  (R5-measured 0 conflicts).
// ---------------------------------------------------------------------------
__global__ __launch_bounds__(256, 2) void mnrl_gemm_lse(
    const unsigned char* __restrict__ A8, const unsigned char* __restrict__ P8,
    float* __restrict__ rowsum, float* __restrict__ diag,
    int* __restrict__ counter, float* __restrict__ out) {
    __shared__ __align__(16) unsigned char lds_a[128 * 128];
    __shared__ __align__(16) unsigned char lds_b[128 * 128];

    // GROUP_M=8 swizzle for L2 locality
    int pid = blockIdx.x;
    const int num_in_group = 8 * TILES;
    int group_id = pid / num_in_group;
    int tile_m = group_id * 8 + (pid % 8);
    int tile_n = (pid % num_in_group) / 8;

    int t = threadIdx.x;
    int lane = t & 63;
    int wave = t >> 6;
    int wm = wave >> 1, wn = wave & 1;
    int quad = lane >> 4;
    int l16 = lane & 15;

    const unsigned char* Abase = A8 + (size_t)tile_m * 128 * ND;
    const unsigned char* Pbase = P8 + (size_t)tile_n * 128 * ND;

    // Staging addresses for this thread's 4 chunks per matrix.
    size_t goff[4];
    int wbyte[4];
#pragma unroll
    for (int i = 0; i < 4; ++i) {
        int c = t + 256 * i;        // 0..1023
        int row = c >> 3;           // 0..127
        int ch = c & 7;
        goff[i] = (size_t)row * ND + ch * 16;
        wbyte[i] = row * 128 + ((ch ^ (row & 7)) * 16);
    }
    int sw7 = l16 & 7;              // frag-read swizzle key

    floatx4 acc[4][4];
#pragma unroll
    for (int i = 0; i < 4; ++i)
#pragma unroll
        for (int j = 0; j < 4; ++j) acc[i][j] = (floatx4){0.f, 0.f, 0.f, 0.f};

    // Prologue: prefetch iter 0 into registers.
    int4 pa[4], pb[4];
#pragma unroll
    for (int i = 0; i < 4; ++i) {
        pa[i] = *(const int4*)(Abase + goff[i]);
        pb[i] = *(const int4*)(Pbase + goff[i]);
    }

    for (int it = 0; it < ND / 128; ++it) {
        if (it) __syncthreads();   // all frag reads of iter it-1 done
        // Stage iter it (s_waitcnt vmcnt lands here — full iter of slack)
#pragma unroll
        for (int i = 0; i < 4; ++i) {
            *(int4*)(lds_a + wbyte[i]) = pa[i];
            *(int4*)(lds_b + wbyte[i]) = pb[i];
        }
        __syncthreads();           // staged data visible (lgkm only)

        // Issue prefetch for iter it+1 (consumed at next iter's top)
        if (it + 1 < ND / 128) {
            size_t koff = (size_t)(it + 1) * 128;
#pragma unroll
            for (int i = 0; i < 4; ++i) {
                pa[i] = *(const int4*)(Abase + goff[i] + koff);
                pb[i] = *(const int4*)(Pbase + goff[i] + koff);
            }
        }

        // Compute iter it.
#pragma unroll
        for (int spl = 0; spl < 2; ++spl) {
            int slot = ((spl * 4 + quad) ^ sw7) * 16;
            longx2 af[4], bfr[4];
#pragma unroll
            for (int mt = 0; mt < 4; ++mt) {
                int R = wm * 64 + mt * 16 + l16;
                af[mt] = *(const longx2*)&lds_a[R * 128 + slot];
            }
#pragma unroll
            for (int nt = 0; nt < 4; ++nt) {
                int R = wn * 64 + nt * 16 + l16;
                bfr[nt] = *(const longx2*)&lds_b[R * 128 + slot];
            }
#pragma unroll
            for (int mt = 0; mt < 4; ++mt)
#pragma unroll
                for (int nt = 0; nt < 4; ++nt)
                    acc[mt][nt] = __builtin_amdgcn_mfma_f32_16x16x32_fp8_fp8(
                        af[mt].x, bfr[nt].x, acc[mt][nt], 0, 0, 0);
#pragma unroll
            for (int mt = 0; mt < 4; ++mt)
#pragma unroll
                for (int nt = 0; nt < 4; ++nt)
                    acc[mt][nt] = __builtin_amdgcn_mfma_f32_16x16x32_fp8_fp8(
                        af[mt].y, bfr[nt].y, acc[mt][nt], 0, 0, 0);
        }
    }

    // Epilogue. C/D layout: col = l16, row = quad*4 + reg.
    int row0 = tile_m * 128 + wm * 64;
    int col0 = tile_n * 128 + wn * 64;
    bool diag_block = (tile_m == tile_n);

    float psum[4][4];
#pragma unroll
    for (int mt = 0; mt < 4; ++mt)
#pragma unroll
        for (int r = 0; r < 4; ++r) psum[mt][r] = 0.0f;

#pragma unroll
    for (int mt = 0; mt < 4; ++mt) {
#pragma unroll
        for (int nt = 0; nt < 4; ++nt) {
#pragma unroll
            for (int r = 0; r < 4; ++r) {
                float sc = EPI_SCALE * acc[mt][nt][r];
                psum[mt][r] += __expf(sc - SCALEF);  // scores in [-20,20]
                if (diag_block) {
                    int grow = row0 + mt * 16 + quad * 4 + r;
                    int gcol = col0 + nt * 16 + l16;
                    if (grow == gcol) diag[grow] = sc;
                }
            }
        }
    }

#pragma unroll
    for (int mt = 0; mt < 4; ++mt) {
#pragma unroll
        for (int r = 0; r < 4; ++r) {
            float v = psum[mt][r];
            v += __shfl_xor(v, 1, 64);
            v += __shfl_xor(v, 2, 64);
            v += __shfl_xor(v, 4, 64);
            v += __shfl_xor(v, 8, 64);
            if (l16 == 0) atomicAdd(&rowsum[row0 + mt * 16 + quad * 4 + r], v);
        }
    }

    // -------- fused finalize: last block computes the loss ----------------
    __threadfence();
    __shared__ int is_last;
    if (t == 0) {
        int old = __hip_atomic_fetch_add(counter, 1, __ATOMIC_ACQ_REL,
                                         __HIP_MEMORY_SCOPE_AGENT);
        is_last = (old == GRID - 1);
    }
    __syncthreads();
    if (is_last) {
        float local = 0.0f;
        for (int i = t; i < NB; i += 256) {
            float rs = __hip_atomic_load(&rowsum[i], __ATOMIC_RELAXED,
                                         __HIP_MEMORY_SCOPE_AGENT);
            float dg = __hip_atomic_load(&diag[i], __ATOMIC_RELAXED,
                                         __HIP_MEMORY_SCOPE_AGENT);
            local += (logf(rs) + SCALEF) - dg;
        }
#pragma unroll
        for (int off = 32; off > 0; off >>= 1) local += __shfl_down(local, off, 64);
        __shared__ float sred[4];
        if ((t & 63) == 0) sred[t >> 6] = local;
        __syncthreads();
        if (t == 0) out[0] = (sred[0] + sred[1] + sred[2] + sred[3]) / (float)NB;
    }
}

// ---------------------------------------------------------------------------
extern "C" void kernel_launch(void* const* d_in, const int* in_sizes, int n_in,
                              void* d_out, int out_size, void* d_ws, size_t ws_size,
                              hipStream_t stream) {
    const float* A = (const float*)d_in[0];
    const float* P = (const float*)d_in[1];

    unsigned char* A8 = (unsigned char*)d_ws;           // 4 MiB (permuted fp8)
    unsigned char* P8 = A8 + (size_t)NB * ND;           // 4 MiB
    float* rowsum = (float*)(P8 + (size_t)NB * ND);     // 16 KiB
    float* diag = rowsum + NB;                          // 16 KiB
    int* counter = (int*)(diag + NB);                   // 4 B

    mnrl_norm_cvt<<<2 * NB / 4, 256, 0, stream>>>(A, P, A8, P8, rowsum, counter);
    mnrl_gemm_lse<<<GRID, 256, 0, stream>>>(A8, P8, rowsum, diag, counter,
                                            (float*)d_out);
}

// Round 7
// 239.753 us; speedup vs baseline: 1.2707x; 1.2707x over previous
//
#include <hip/hip_runtime.h>
#include <math.h>

#define NB 4096
#define ND 1024
#define SCALEF 20.0f
#define TILES 32   // 4096 / 128 tiles per dimension
#define GRID (TILES * TILES)
// epilogue compensation: elements scaled by 256 at convert -> dot x 65536
#define EPI_SCALE (SCALEF / 65536.0f)

typedef float floatx4 __attribute__((ext_vector_type(4)));
typedef long longx2 __attribute__((ext_vector_type(2)));

// ---------------------------------------------------------------------------
// Kernel 1: fused L2-normalize + scale-by-256 + fp32->fp8(e4m3 OCP) convert.
// Permuted row layout, MFMA-fragment order: element k = s*32 + q*8 + j
// (s = K32 step, q = quad, j = 0..7) lives at byte
//   pos(k) = (s>>1)*64 + q*16 + (s&1)*8 + j
// i.e. a 16-B cell holds one quad's operands for K32 steps 2sp,2sp+1 —
// exactly one global_load_dwordx4 per MFMA operand pair in the GEMM.
// One wave per row; lane l handles cell l. Also zeroes rowsum[] + counter.
// ---------------------------------------------------------------------------
__global__ __launch_bounds__(256) void mnrl_norm_cvt(
    const float* __restrict__ A, const float* __restrict__ P,
    unsigned char* __restrict__ A8, unsigned char* __restrict__ P8,
    float* __restrict__ rowsum, int* __restrict__ counter) {
    int row = blockIdx.x * 4 + (threadIdx.x >> 6);  // 0..8191
    int lane = threadIdx.x & 63;
    bool is_a = row < NB;
    const float* src = is_a ? (A + (size_t)row * ND)
                            : (P + (size_t)(row - NB) * ND);
    unsigned char* dst = is_a ? (A8 + (size_t)row * ND)
                              : (P8 + (size_t)(row - NB) * ND);

    int g0 = (lane >> 2) * 64 + (lane & 3) * 8;  // k of step 2sp, quad q
    float4 va = *(const float4*)(src + g0);
    float4 vb = *(const float4*)(src + g0 + 4);
    float4 vc = *(const float4*)(src + g0 + 32);  // step 2sp+1
    float4 vd = *(const float4*)(src + g0 + 36);

    float ss = va.x * va.x + va.y * va.y + va.z * va.z + va.w * va.w +
               vb.x * vb.x + vb.y * vb.y + vb.z * vb.z + vb.w * vb.w +
               vc.x * vc.x + vc.y * vc.y + vc.z * vc.z + vc.w * vc.w +
               vd.x * vd.x + vd.y * vd.y + vd.z * vd.z + vd.w * vd.w;
#pragma unroll
    for (int off = 32; off > 0; off >>= 1) ss += __shfl_xor(ss, off, 64);
    float inv = 256.0f / fmaxf(sqrtf(ss), 1e-8f);  // 256x folded in here

    int w0 = __builtin_amdgcn_cvt_pk_fp8_f32(va.x * inv, va.y * inv, 0, false);
    w0 = __builtin_amdgcn_cvt_pk_fp8_f32(va.z * inv, va.w * inv, w0, true);
    int w1 = __builtin_amdgcn_cvt_pk_fp8_f32(vb.x * inv, vb.y * inv, 0, false);
    w1 = __builtin_amdgcn_cvt_pk_fp8_f32(vb.z * inv, vb.w * inv, w1, true);
    int w2 = __builtin_amdgcn_cvt_pk_fp8_f32(vc.x * inv, vc.y * inv, 0, false);
    w2 = __builtin_amdgcn_cvt_pk_fp8_f32(vc.z * inv, vc.w * inv, w2, true);
    int w3 = __builtin_amdgcn_cvt_pk_fp8_f32(vd.x * inv, vd.y * inv, 0, false);
    w3 = __builtin_amdgcn_cvt_pk_fp8_f32(vd.z * inv, vd.w * inv, w3, true);
    int4 w; w.x = w0; w.y = w1; w.z = w2; w.w = w3;
    *(int4*)(dst + lane * 16) = w;

    if (is_a && lane == 0) rowsum[row] = 0.0f;
    if (blockIdx.x == 0 && threadIdx.x == 0) *counter = 0;
}

// ---------------------------------------------------------------------------
// Kernel 2: 128x128-tile fp8 MFMA GEMM, NO LDS, NO K-loop barriers.
// Inputs are tiny (8 MB, L2/L3-resident) and stored in fragment order, so
// each lane global_load_dwordx4's its own MFMA operands directly. Waves are
// fully decoupled — per-wave load latency is hidden by other waves' MFMAs
// (no barrier ever couples them). Fused exp-sum + diag + last-block finalize.
// ---------------------------------------------------------------------------
__global__ __launch_bounds__(256) void mnrl_gemm_lse(
    const unsigned char* __restrict__ A8, const unsigned char* __restrict__ P8,
    float* __restrict__ rowsum, float* __restrict__ diag,
    int* __restrict__ counter, float* __restrict__ out) {
    // GROUP_M=8 swizzle for L2 locality
    int pid = blockIdx.x;
    const int num_in_group = 8 * TILES;
    int group_id = pid / num_in_group;
    int tile_m = group_id * 8 + (pid % 8);
    int tile_n = (pid % num_in_group) / 8;

    int t = threadIdx.x;
    int lane = t & 63;
    int wave = t >> 6;
    int wm = wave >> 1, wn = wave & 1;
    int quad = lane >> 4;
    int l16 = lane & 15;

    // Per-lane fragment base pointers (fragment-order layout).
    const unsigned char* aP =
        A8 + ((size_t)(tile_m * 128 + wm * 64 + l16)) * ND + quad * 16;
    const unsigned char* bP =
        P8 + ((size_t)(tile_n * 128 + wn * 64 + l16)) * ND + quad * 16;

    floatx4 acc[4][4];
#pragma unroll
    for (int i = 0; i < 4; ++i)
#pragma unroll
        for (int j = 0; j < 4; ++j) acc[i][j] = (floatx4){0.f, 0.f, 0.f, 0.f};

    for (int it = 0; it < ND / 128; ++it) {
#pragma unroll
        for (int spl = 0; spl < 2; ++spl) {
            int off = it * 128 + spl * 64;
            longx2 af[4], bfr[4];
#pragma unroll
            for (int mt = 0; mt < 4; ++mt)
                af[mt] = *(const longx2*)(aP + (size_t)mt * 16 * ND + off);
#pragma unroll
            for (int nt = 0; nt < 4; ++nt)
                bfr[nt] = *(const longx2*)(bP + (size_t)nt * 16 * ND + off);
            // .x = K32 step 2*(it*2+spl), .y = next step
#pragma unroll
            for (int mt = 0; mt < 4; ++mt)
#pragma unroll
                for (int nt = 0; nt < 4; ++nt)
                    acc[mt][nt] = __builtin_amdgcn_mfma_f32_16x16x32_fp8_fp8(
                        af[mt].x, bfr[nt].x, acc[mt][nt], 0, 0, 0);
#pragma unroll
            for (int mt = 0; mt < 4; ++mt)
#pragma unroll
                for (int nt = 0; nt < 4; ++nt)
                    acc[mt][nt] = __builtin_amdgcn_mfma_f32_16x16x32_fp8_fp8(
                        af[mt].y, bfr[nt].y, acc[mt][nt], 0, 0, 0);
        }
    }

    // Epilogue. C/D layout: col = l16, row = quad*4 + reg.
    int row0 = tile_m * 128 + wm * 64;
    int col0 = tile_n * 128 + wn * 64;
    bool diag_block = (tile_m == tile_n);

    float psum[4][4];
#pragma unroll
    for (int mt = 0; mt < 4; ++mt)
#pragma unroll
        for (int r = 0; r < 4; ++r) psum[mt][r] = 0.0f;

#pragma unroll
    for (int mt = 0; mt < 4; ++mt) {
#pragma unroll
        for (int nt = 0; nt < 4; ++nt) {
#pragma unroll
            for (int r = 0; r < 4; ++r) {
                float sc = EPI_SCALE * acc[mt][nt][r];
                psum[mt][r] += __expf(sc - SCALEF);  // scores in [-20,20]
                if (diag_block) {
                    int grow = row0 + mt * 16 + quad * 4 + r;
                    int gcol = col0 + nt * 16 + l16;
                    if (grow == gcol) diag[grow] = sc;
                }
            }
        }
    }

#pragma unroll
    for (int mt = 0; mt < 4; ++mt) {
#pragma unroll
        for (int r = 0; r < 4; ++r) {
            float v = psum[mt][r];
            v += __shfl_xor(v, 1, 64);
            v += __shfl_xor(v, 2, 64);
            v += __shfl_xor(v, 4, 64);
            v += __shfl_xor(v, 8, 64);
            if (l16 == 0) atomicAdd(&rowsum[row0 + mt * 16 + quad * 4 + r], v);
        }
    }

    // -------- fused finalize: last block computes the loss ----------------
    __threadfence();
    __shared__ int is_last;
    if (t == 0) {
        int old = __hip_atomic_fetch_add(counter, 1, __ATOMIC_ACQ_REL,
                                         __HIP_MEMORY_SCOPE_AGENT);
        is_last = (old == GRID - 1);
    }
    __syncthreads();
    if (is_last) {
        float local = 0.0f;
        for (int i = t; i < NB; i += 256) {
            float rs = __hip_atomic_load(&rowsum[i], __ATOMIC_RELAXED,
                                         __HIP_MEMORY_SCOPE_AGENT);
            float dg = __hip_atomic_load(&diag[i], __ATOMIC_RELAXED,
                                         __HIP_MEMORY_SCOPE_AGENT);
            local += (logf(rs) + SCALEF) - dg;
        }
#pragma unroll
        for (int off = 32; off > 0; off >>= 1) local += __shfl_down(local, off, 64);
        __shared__ float sred[4];
        if ((t & 63) == 0) sred[t >> 6] = local;
        __syncthreads();
        if (t == 0) out[0] = (sred[0] + sred[1] + sred[2] + sred[3]) / (float)NB;
    }
}

// ---------------------------------------------------------------------------
extern "C" void kernel_launch(void* const* d_in, const int* in_sizes, int n_in,
                              void* d_out, int out_size, void* d_ws, size_t ws_size,
                              hipStream_t stream) {
    const float* A = (const float*)d_in[0];
    const float* P = (const float*)d_in[1];

    unsigned char* A8 = (unsigned char*)d_ws;           // 4 MiB (fragment-order fp8)
    unsigned char* P8 = A8 + (size_t)NB * ND;           // 4 MiB
    float* rowsum = (float*)(P8 + (size_t)NB * ND);     // 16 KiB
    float* diag = rowsum + NB;                          // 16 KiB
    int* counter = (int*)(diag + NB);                   // 4 B

    mnrl_norm_cvt<<<2 * NB / 4, 256, 0, stream>>>(A, P, A8, P8, rowsum, counter);
    mnrl_gemm_lse<<<GRID, 256, 0, stream>>>(A8, P8, rowsum, diag, counter,
                                            (float*)d_out);
}